// Round 16
// baseline (201.427 us; speedup 1.0000x reference)
//
#include <hip/hip_runtime.h>
#include <hip/hip_bf16.h>

// MultiHeadedAttention: B=4, S=1024, D=1024, H=16, DK=64
// Inputs FLOAT32 (q,k,v,gp,W*,b*) + int32 mask. Output FLOAT32 [B,S,D].
// R16: (1) weights pre-converted to bf16 once (W panels were re-cast 32x per
// GEMM block); (2) GEMMs use single-barrier double-buffered LDS loops (64->32
// barriers); (3) G2 stored bf16 (fits 42MB ws, -1 sentinel exact). attn core
// unchanged from R15 (it left the top-5).

#define AS1q __attribute__((address_space(1)))
#define AS3q __attribute__((address_space(3)))

typedef __attribute__((ext_vector_type(8))) __bf16 bf16x8;
typedef __attribute__((ext_vector_type(4))) float f32x4;
typedef __attribute__((ext_vector_type(8))) unsigned short u16x8;

#define GSTR 40  // GEMM LDS row stride in shorts (80B, 16B-aligned)

__device__ __forceinline__ void gload_lds16(const void* g, void* l) {
  __builtin_amdgcn_global_load_lds((const AS1q void*)g, (AS3q void*)l, 16, 0, 0);
}
// TBAA-safe 16B accessors (byte-typed memcpy: ordered vs scalar stores)
__device__ __forceinline__ bf16x8 lds_read8(const unsigned short* p) {
  bf16x8 r;
  __builtin_memcpy(&r, __builtin_assume_aligned(p, 16), 16);
  return r;
}
__device__ __forceinline__ void lds_write8(unsigned short* p, const void* v) {
  __builtin_memcpy(__builtin_assume_aligned(p, 16), v, 16);
}
__device__ __forceinline__ float bf2f(unsigned short u) {
  union { unsigned int i; float f; } v; v.i = ((unsigned int)u) << 16; return v.f;
}
__device__ __forceinline__ u16x8 cvt8h(const float4 a, const float4 b) {
  const float fv[8] = {a.x, a.y, a.z, a.w, b.x, b.y, b.z, b.w};
  union { u16x8 v; __bf16 e[8]; } hh;
#pragma unroll
  for (int i = 0; i < 8; ++i) hh.e[i] = (__bf16)fv[i];
  return hh.v;
}
__device__ __forceinline__ void cvt8hl(const float4 a, const float4 b, u16x8* hi, u16x8* lo) {
  const float fv[8] = {a.x, a.y, a.z, a.w, b.x, b.y, b.z, b.w};
  union { u16x8 v; __bf16 e[8]; } hh, ll;
#pragma unroll
  for (int i = 0; i < 8; ++i) {
    const __bf16 h = (__bf16)fv[i];
    hh.e[i] = h;
    ll.e[i] = (__bf16)(fv[i] - (float)h);
  }
  *hi = hh.v; *lo = ll.v;
}
__device__ __forceinline__ unsigned short bfbits(float f) {
  const __bf16 h = (__bf16)f;
  unsigned short u; __builtin_memcpy(&u, &h, 2); return u;
}

// ---- prep: G2 = bf16((mask | diag) ? gp : -1.0f), 8 elems/thread ----
__global__ __launch_bounds__(256) void k_prep_g2(
    const int* __restrict__ Mask, const float* __restrict__ Gp,
    unsigned short* __restrict__ G2)
{
  const size_t e = ((size_t)blockIdx.x * 256 + threadIdx.x) * 8;
  const int k0 = (int)(e & 1023), q = (int)((e >> 10) & 1023);
  const int4 m0 = *(const int4*)(Mask + e);
  const int4 m1 = *(const int4*)(Mask + e + 4);
  const float4 g0 = *(const float4*)(Gp + e);
  const float4 g1 = *(const float4*)(Gp + e + 4);
  const int mm[8] = {m0.x, m0.y, m0.z, m0.w, m1.x, m1.y, m1.z, m1.w};
  const float gg[8] = {g0.x, g0.y, g0.z, g0.w, g1.x, g1.y, g1.z, g1.w};
  union { u16x8 v; unsigned short s[8]; } r;
#pragma unroll
  for (int i = 0; i < 8; ++i)
    r.s[i] = bfbits((mm[i] | (q == k0 + i)) ? gg[i] : -1.f);
  *(u16x8*)(G2 + e) = r.v;
}

// ---- prep: weights -> bf16 (Wq/Wk/Wv plain; Wo split hi/lo), 8 elems/thread ----
__global__ __launch_bounds__(256) void k_prep_w(
    const float* __restrict__ Wq, const float* __restrict__ Wk,
    const float* __restrict__ Wv, const float* __restrict__ Wo,
    unsigned short* __restrict__ Qw, unsigned short* __restrict__ Kw,
    unsigned short* __restrict__ Vw, unsigned short* __restrict__ Oh,
    unsigned short* __restrict__ Ol)
{
  const int z = blockIdx.z;
  const size_t e = ((size_t)blockIdx.x * 256 + threadIdx.x) * 8;
  if (z < 3) {
    const float* S = (z == 0) ? Wq : (z == 1) ? Wk : Wv;
    unsigned short* D = (z == 0) ? Qw : (z == 1) ? Kw : Vw;
    const float4 a = *(const float4*)(S + e);
    const float4 b = *(const float4*)(S + e + 4);
    *(u16x8*)(D + e) = cvt8h(a, b);
  } else {
    const float4 a = *(const float4*)(Wo + e);
    const float4 b = *(const float4*)(Wo + e + 4);
    u16x8 hi, lo;
    cvt8hl(a, b, &hi, &lo);
    *(u16x8*)(Oh + e) = hi;
    *(u16x8*)(Ol + e) = lo;
  }
}

// ---- QKV GEMM, 128x64 tile, BK=32, bf16 W, single-barrier dbuf, bf16 out ----
__global__ __launch_bounds__(256) void k_gemm_qkv(
    const float* __restrict__ X0, const float* __restrict__ X1, const float* __restrict__ X2,
    const unsigned short* __restrict__ W0, const unsigned short* __restrict__ W1,
    const unsigned short* __restrict__ W2,
    const float* __restrict__ B0, const float* __restrict__ B1, const float* __restrict__ B2,
    unsigned short* __restrict__ O0, unsigned short* __restrict__ O1,
    unsigned short* __restrict__ O2)
{
  const int z = blockIdx.z;
  const float* X = (z == 0) ? X0 : (z == 1) ? X1 : X2;
  const unsigned short* W = (z == 0) ? W0 : (z == 1) ? W1 : W2;
  const float* Bi = (z == 0) ? B0 : (z == 1) ? B1 : B2;
  unsigned short* O = (z == 0) ? O0 : (z == 1) ? O1 : O2;

  const int bid = blockIdx.x;
  const int swz = (bid & 7) * 64 + (bid >> 3);
  const int n0 = (swz & 15) * 64, m0 = (swz >> 4) * 128;

  __shared__ alignas(16) unsigned short Ah[2][128 * GSTR];  // 20KB
  __shared__ alignas(16) unsigned short Bh[2][64 * GSTR];   // 10KB
  const int tid = threadIdx.x, l = tid & 63, w = tid >> 6;
  const int wr = w >> 1, wc = w & 1;

  f32x4 acc[4][2];
#pragma unroll
  for (int i = 0; i < 4; ++i)
#pragma unroll
    for (int j = 0; j < 2; ++j) acc[i][j] = (f32x4){0.f, 0.f, 0.f, 0.f};

  const int arow = tid >> 1, ac0 = (tid & 1) * 16;   // A: 128 rows x 32 k (f32)
  const int brow = tid >> 2, bc0 = (tid & 3) * 8;    // B:  64 rows x 32 k (bf16)
  const float* xsrc = X + (size_t)(m0 + arow) * 1024 + ac0;
  const unsigned short* wsrc = W + (size_t)(n0 + brow) * 1024 + bc0;

  float4 fx[4];
  u16x8 bx;
  // tile 0 -> regs -> buf0
#pragma unroll
  for (int i = 0; i < 4; ++i) fx[i] = *(const float4*)(xsrc + i * 4);
  bx = *(const u16x8*)(wsrc);
  {
    const u16x8 a0 = cvt8h(fx[0], fx[1]), a1 = cvt8h(fx[2], fx[3]);
    lds_write8(&Ah[0][arow * GSTR + ac0], &a0);
    lds_write8(&Ah[0][arow * GSTR + ac0 + 8], &a1);
    lds_write8(&Bh[0][brow * GSTR + bc0], &bx);
  }
  // tile 1 -> regs
#pragma unroll
  for (int i = 0; i < 4; ++i) fx[i] = *(const float4*)(xsrc + 32 + i * 4);
  bx = *(const u16x8*)(wsrc + 32);

  int buf = 0;
  for (int kt = 0; kt < 32; ++kt) {
    __syncthreads();  // buf's tile fully written (prev iter); prev reads done
    if (kt < 31) {
      const u16x8 a0 = cvt8h(fx[0], fx[1]), a1 = cvt8h(fx[2], fx[3]);
      lds_write8(&Ah[buf ^ 1][arow * GSTR + ac0], &a0);
      lds_write8(&Ah[buf ^ 1][arow * GSTR + ac0 + 8], &a1);
      lds_write8(&Bh[buf ^ 1][brow * GSTR + bc0], &bx);
      if (kt < 30) {
        const float* nx = xsrc + (kt + 2) * 32;
#pragma unroll
        for (int i = 0; i < 4; ++i) fx[i] = *(const float4*)(nx + i * 4);
        bx = *(const u16x8*)(wsrc + (kt + 2) * 32);
      }
    }
    bf16x8 ah[4], bh[2];
#pragma unroll
    for (int mf = 0; mf < 4; ++mf) {
      const int r = wr * 64 + mf * 16 + (l & 15);
      ah[mf] = lds_read8(&Ah[buf][r * GSTR + (l >> 4) * 8]);
    }
#pragma unroll
    for (int nf = 0; nf < 2; ++nf) {
      const int r = wc * 32 + nf * 16 + (l & 15);
      bh[nf] = lds_read8(&Bh[buf][r * GSTR + (l >> 4) * 8]);
    }
#pragma unroll
    for (int mf = 0; mf < 4; ++mf)
#pragma unroll
      for (int nf = 0; nf < 2; ++nf)
        acc[mf][nf] = __builtin_amdgcn_mfma_f32_16x16x32_bf16(ah[mf], bh[nf], acc[mf][nf], 0, 0, 0);
    buf ^= 1;
  }

#pragma unroll
  for (int nf = 0; nf < 2; ++nf) {
    const int col = n0 + wc * 32 + nf * 16 + (l & 15);
    const float bias = Bi[col];
#pragma unroll
    for (int mf = 0; mf < 4; ++mf) {
      const int rbase = m0 + wr * 64 + mf * 16 + (l >> 4) * 4;
#pragma unroll
      for (int j = 0; j < 4; ++j)
        O[(size_t)(rbase + j) * 1024 + col] = bfbits(acc[mf][nf][j] + bias);
    }
  }
}

// ---- out-proj GEMM, 64x64 tile, BK=32, all-bf16 staging, single-barrier dbuf ----
__global__ __launch_bounds__(256) void k_gemm_out(
    const unsigned short* __restrict__ X, const unsigned short* __restrict__ Wh,
    const unsigned short* __restrict__ Wl, const float* __restrict__ Bi,
    float* __restrict__ Out)
{
  const int bid = blockIdx.x;
  const int swz = (bid & 7) * 128 + (bid >> 3);
  const int n0 = (swz & 15) * 64, m0 = (swz >> 4) * 64;

  __shared__ alignas(16) unsigned short Ah[2][64 * GSTR];
  __shared__ alignas(16) unsigned short Bh[2][64 * GSTR], Bl[2][64 * GSTR];  // 30KB
  const int tid = threadIdx.x, l = tid & 63, w = tid >> 6;
  const int wr = w >> 1, wc = w & 1;

  f32x4 acc[2][2];
#pragma unroll
  for (int i = 0; i < 2; ++i)
#pragma unroll
    for (int j = 0; j < 2; ++j) acc[i][j] = (f32x4){0.f, 0.f, 0.f, 0.f};

  const int srow = tid >> 2, sc0 = (tid & 3) * 8;
  const unsigned short* xsrc = X + (size_t)(m0 + srow) * 1024 + sc0;
  const unsigned short* whs = Wh + (size_t)(n0 + srow) * 1024 + sc0;
  const unsigned short* wls = Wl + (size_t)(n0 + srow) * 1024 + sc0;

  u16x8 xa = *(const u16x8*)xsrc, wa = *(const u16x8*)whs, la = *(const u16x8*)wls;
  lds_write8(&Ah[0][srow * GSTR + sc0], &xa);
  lds_write8(&Bh[0][srow * GSTR + sc0], &wa);
  lds_write8(&Bl[0][srow * GSTR + sc0], &la);
  xa = *(const u16x8*)(xsrc + 32);
  wa = *(const u16x8*)(whs + 32);
  la = *(const u16x8*)(wls + 32);

  int buf = 0;
  for (int kt = 0; kt < 32; ++kt) {
    __syncthreads();
    if (kt < 31) {
      lds_write8(&Ah[buf ^ 1][srow * GSTR + sc0], &xa);
      lds_write8(&Bh[buf ^ 1][srow * GSTR + sc0], &wa);
      lds_write8(&Bl[buf ^ 1][srow * GSTR + sc0], &la);
      if (kt < 30) {
        xa = *(const u16x8*)(xsrc + (kt + 2) * 32);
        wa = *(const u16x8*)(whs + (kt + 2) * 32);
        la = *(const u16x8*)(wls + (kt + 2) * 32);
      }
    }
    bf16x8 ah[2], bh[2], bl[2];
#pragma unroll
    for (int mf = 0; mf < 2; ++mf) {
      const int r = wr * 32 + mf * 16 + (l & 15);
      ah[mf] = lds_read8(&Ah[buf][r * GSTR + (l >> 4) * 8]);
    }
#pragma unroll
    for (int nf = 0; nf < 2; ++nf) {
      const int r = wc * 32 + nf * 16 + (l & 15);
      bh[nf] = lds_read8(&Bh[buf][r * GSTR + (l >> 4) * 8]);
      bl[nf] = lds_read8(&Bl[buf][r * GSTR + (l >> 4) * 8]);
    }
#pragma unroll
    for (int mf = 0; mf < 2; ++mf)
#pragma unroll
      for (int nf = 0; nf < 2; ++nf) {
        acc[mf][nf] = __builtin_amdgcn_mfma_f32_16x16x32_bf16(ah[mf], bh[nf], acc[mf][nf], 0, 0, 0);
        acc[mf][nf] = __builtin_amdgcn_mfma_f32_16x16x32_bf16(ah[mf], bl[nf], acc[mf][nf], 0, 0, 0);
      }
    buf ^= 1;
  }

#pragma unroll
  for (int nf = 0; nf < 2; ++nf) {
    const int col = n0 + wc * 32 + nf * 16 + (l & 15);
    const float bias = Bi[col];
#pragma unroll
    for (int mf = 0; mf < 2; ++mf) {
      const int rbase = m0 + wr * 32 + mf * 16 + (l >> 4) * 4;
#pragma unroll
      for (int j = 0; j < 4; ++j)
        Out[(size_t)(rbase + j) * 1024 + col] = acc[mf][nf][j] + bias;
    }
  }
}

// ---------------- fused attention (R15 structure, bf16 G2) ----------------
__global__ __launch_bounds__(256) void k_attn(
    const unsigned short* Qh, const unsigned short* __restrict__ Kb,
    const unsigned short* __restrict__ Vb,
    const unsigned short* __restrict__ G2, unsigned short* Xo)
{
  const int i = blockIdx.x;
  const int xc = i & 7, kk_ = i >> 3;
  const int h = kk_ & 15, g = kk_ >> 4;
  const int qb = g * 8 + xc;
  const int qt = qb >> 2, b = qb & 3;

  __shared__ alignas(16) unsigned short Kh[2][64 * 64];
  __shared__ alignas(16) unsigned short Vh[64 * 64];
  __shared__ alignas(16) unsigned short Ph[64 * 64];
  const int tid = threadIdx.x, l = tid & 63, w = tid >> 6;

  const unsigned short* kb_ = Kb + (size_t)b * 1048576 + h * 64;
  const unsigned short* vb_ = Vb + (size_t)b * 1048576 + h * 64;

  bf16x8 aq[2];
  {
    const int qrow = qt * 64 + w * 16 + (l & 15);
    const unsigned short* qp_ = Qh + ((size_t)(b * 1024 + qrow)) * 1024 + h * 64;
    aq[0] = lds_read8(qp_ + (l >> 4) * 8);
    aq[1] = lds_read8(qp_ + 32 + (l >> 4) * 8);
  }

  f32x4 accO[4];
#pragma unroll
  for (int nf = 0; nf < 4; ++nf) accO[nf] = (f32x4){0.f, 0.f, 0.f, 0.f};
  float zacc[4] = {0.f, 0.f, 0.f, 0.f};

  const int qloc0 = w * 16 + (l >> 4) * 4;
  const int qg0 = qt * 64 + qloc0;
  const int mcol = l & 15;

  const unsigned short* grow[4];
#pragma unroll
  for (int j = 0; j < 4; ++j)
    grow[j] = G2 + (((size_t)(b * 1024 + qg0 + j)) << 10) + mcol;

  const int srcg8 = ((l & 7) ^ (l >> 3)) * 8;
  const int rowl = l >> 3;
  const int kb4 = (tid & 15) * 4, db4 = (tid >> 4) * 4;
  union U4 { unsigned int u[2]; unsigned short s[4]; };
  U4 vr[4];

#pragma unroll
  for (int I = 0; I < 2; ++I)
    gload_lds16(kb_ + (size_t)(I * 32 + w * 8 + rowl) * 1024 + srcg8,
                &Kh[0][I * 2048 + w * 512]);
#pragma unroll
  for (int ii = 0; ii < 4; ++ii)
    __builtin_memcpy(&vr[ii], vb_ + (size_t)(kb4 + ii) * 1024 + db4, 8);

  float gcur[4][4], gnext[4][4];
#pragma unroll
  for (int nf = 0; nf < 4; ++nf)
#pragma unroll
    for (int j = 0; j < 4; ++j) gcur[nf][j] = bf2f(grow[j][nf * 16]);

  int buf = 0;
  for (int kt = 0; kt < 16; ++kt) {
    __syncthreads();  // B1: drains K[buf] gl_lds + vr loads; prev tile consumed

#pragma unroll
    for (int ii = 0; ii < 4; ++ii) {
      const int d = db4 + ii;
      union { unsigned short s[4]; unsigned long long v; } pk;
#pragma unroll
      for (int u = 0; u < 4; ++u) pk.s[u] = vr[u].s[ii];
      const int c = kb4 ^ ((d & 7) << 3);
      __builtin_memcpy(__builtin_assume_aligned(&Vh[d * 64 + c], 8), &pk.v, 8);
    }
    __syncthreads();  // B2: V + K[buf] ready

    if (kt < 15) {
#pragma unroll
      for (int I = 0; I < 2; ++I)
        gload_lds16(kb_ + (size_t)((kt + 1) * 64 + I * 32 + w * 8 + rowl) * 1024 + srcg8,
                    &Kh[buf ^ 1][I * 2048 + w * 512]);
#pragma unroll
      for (int ii = 0; ii < 4; ++ii)
        __builtin_memcpy(&vr[ii], vb_ + (size_t)((kt + 1) * 64 + kb4 + ii) * 1024 + db4, 8);
#pragma unroll
      for (int nf = 0; nf < 4; ++nf)
#pragma unroll
        for (int j = 0; j < 4; ++j) gnext[nf][j] = bf2f(grow[j][(kt + 1) * 64 + nf * 16]);
    }

#pragma unroll
    for (int nf = 0; nf < 4; ++nf) {
      f32x4 sacc = (f32x4){0.f, 0.f, 0.f, 0.f};
      const int kr = nf * 16 + (l & 15);
#pragma unroll
      for (int ks = 0; ks < 2; ++ks) {
        const int c = (ks * 32 + (l >> 4) * 8) ^ ((kr & 7) << 3);
        sacc = __builtin_amdgcn_mfma_f32_16x16x32_bf16(aq[ks], lds_read8(&Kh[buf][kr * 64 + c]), sacc, 0, 0, 0);
      }
#pragma unroll
      for (int j = 0; j < 4; ++j) {
        const float g2 = gcur[nf][j];
        const float e = (g2 >= 0.f) ? exp2f(fmaf(sacc[j], 0.18033688f, -17.31234049f)) : 0.f;
        zacc[j] += e;
        const int qloc = qloc0 + j;
        Ph[qloc * 64 + ((nf * 16 + mcol) ^ ((qloc & 7) << 3))] = bfbits(e * g2);
      }
    }
    bf16x8 pah[2];
    {
      const int ar = w * 16 + (l & 15);
#pragma unroll
      for (int ks = 0; ks < 2; ++ks) {
        const int c = (ks * 32 + (l >> 4) * 8) ^ ((ar & 7) << 3);
        pah[ks] = lds_read8(&Ph[ar * 64 + c]);
      }
    }
#pragma unroll
    for (int nf = 0; nf < 4; ++nf) {
      const int dr = nf * 16 + (l & 15);
#pragma unroll
      for (int ks = 0; ks < 2; ++ks) {
        const int c = (ks * 32 + (l >> 4) * 8) ^ ((dr & 7) << 3);
        accO[nf] = __builtin_amdgcn_mfma_f32_16x16x32_bf16(pah[ks], lds_read8(&Vh[dr * 64 + c]), accO[nf], 0, 0, 0);
      }
    }
    buf ^= 1;
#pragma unroll
    for (int nf = 0; nf < 4; ++nf)
#pragma unroll
      for (int j = 0; j < 4; ++j) gcur[nf][j] = gnext[nf][j];
  }

#pragma unroll
  for (int j = 0; j < 4; ++j) {
#pragma unroll
    for (int off = 1; off < 16; off <<= 1) zacc[j] += __shfl_xor(zacc[j], off, 64);
  }
  float rz[4];
#pragma unroll
  for (int j = 0; j < 4; ++j) rz[j] = 1.f / zacc[j];

#pragma unroll
  for (int nf = 0; nf < 4; ++nf) {
    const int d = nf * 16 + (l & 15);
#pragma unroll
    for (int j = 0; j < 4; ++j) {
      const int qg = qg0 + j;
      Xo[((size_t)(b * 1024 + qg)) * 1024 + h * 64 + d] = bfbits(accO[nf][j] * rz[j]);
    }
  }
}

extern "C" void kernel_launch(void* const* d_in, const int* in_sizes, int n_in,
                              void* d_out, int out_size, void* d_ws, size_t ws_size,
                              hipStream_t stream) {
  const float* query = (const float*)d_in[0];
  const float* key_in = (const float*)d_in[1];
  const float* value = (const float*)d_in[2];
  const int* mask = (const int*)d_in[3];
  const float* gp = (const float*)d_in[4];
  const float* Wq = (const float*)d_in[5];
  const float* bq = (const float*)d_in[6];
  const float* Wk = (const float*)d_in[7];
  const float* bk = (const float*)d_in[8];
  const float* Wv = (const float*)d_in[9];
  const float* bv = (const float*)d_in[10];
  const float* Wo = (const float*)d_in[11];
  const float* bo = (const float*)d_in[12];
  float* out = (float*)d_out;

  // Workspace 42MB (<48MB proven): kp,vp,qp (bf16, xo aliases qp), g2 bf16,
  // pre-converted weights.
  unsigned short* kp = (unsigned short*)d_ws;
  unsigned short* vp = kp + 4194304;
  unsigned short* qp = vp + 4194304;
  unsigned short* xo = qp;
  unsigned short* g2 = qp + 4194304;
  unsigned short* wq = g2 + 4194304;
  unsigned short* wk = wq + 1048576;
  unsigned short* wv = wk + 1048576;
  unsigned short* woh = wv + 1048576;
  unsigned short* wol = woh + 1048576;

  hipLaunchKernelGGL(k_prep_g2, dim3(2048), dim3(256), 0, stream, mask, gp, g2);
  hipLaunchKernelGGL(k_prep_w, dim3(512, 1, 4), dim3(256), 0, stream,
                     Wq, Wk, Wv, Wo, wq, wk, wv, woh, wol);
  hipLaunchKernelGGL(k_gemm_qkv, dim3(512, 1, 3), dim3(256), 0, stream,
                     query, key_in, value, wq, wk, wv, bq, bk, bv, qp, kp, vp);
  hipLaunchKernelGGL(k_attn, dim3(1024), dim3(256), 0, stream,
                     qp, kp, vp, g2, xo);
  hipLaunchKernelGGL(k_gemm_out, dim3(1024), dim3(256), 0, stream,
                     xo, woh, wol, bo, out);
}

// Round 17
// 178.911 us; speedup vs baseline: 1.1259x; 1.1259x over previous
//
#include <hip/hip_runtime.h>
#include <hip/hip_bf16.h>

// MultiHeadedAttention: B=4, S=1024, D=1024, H=16, DK=64
// Inputs FLOAT32 (q,k,v,gp,W*,b*) + int32 mask. Output FLOAT32 [B,S,D].
// R17 recombination of proven pieces: attn = R15 exact (G2 f32; bf16-G2 cost
// +28us in R16). qkv = R16 (pre-converted bf16 W, single-barrier dbuf; part of
// R16's -13us GEMM gain). out-proj = R15 (in-kernel Wo split, proven).
// prep = G2-f32 + Wq/Wk/Wv->bf16. ws = 46MB (<48 proven).

#define AS1q __attribute__((address_space(1)))
#define AS3q __attribute__((address_space(3)))

typedef __attribute__((ext_vector_type(8))) __bf16 bf16x8;
typedef __attribute__((ext_vector_type(4))) float f32x4;
typedef __attribute__((ext_vector_type(8))) unsigned short u16x8;

#define GSTR 40  // GEMM LDS row stride in shorts (80B, 16B-aligned)

__device__ __forceinline__ void gload_lds16(const void* g, void* l) {
  __builtin_amdgcn_global_load_lds((const AS1q void*)g, (AS3q void*)l, 16, 0, 0);
}
// TBAA-safe 16B accessors (byte-typed memcpy: ordered vs scalar stores)
__device__ __forceinline__ bf16x8 lds_read8(const unsigned short* p) {
  bf16x8 r;
  __builtin_memcpy(&r, __builtin_assume_aligned(p, 16), 16);
  return r;
}
__device__ __forceinline__ void lds_write8(unsigned short* p, const void* v) {
  __builtin_memcpy(__builtin_assume_aligned(p, 16), v, 16);
}
__device__ __forceinline__ u16x8 cvt8h(const float4 a, const float4 b) {
  const float fv[8] = {a.x, a.y, a.z, a.w, b.x, b.y, b.z, b.w};
  union { u16x8 v; __bf16 e[8]; } hh;
#pragma unroll
  for (int i = 0; i < 8; ++i) hh.e[i] = (__bf16)fv[i];
  return hh.v;
}
__device__ __forceinline__ void cvt8hl(const float4 a, const float4 b, u16x8* hi, u16x8* lo) {
  const float fv[8] = {a.x, a.y, a.z, a.w, b.x, b.y, b.z, b.w};
  union { u16x8 v; __bf16 e[8]; } hh, ll;
#pragma unroll
  for (int i = 0; i < 8; ++i) {
    const __bf16 h = (__bf16)fv[i];
    hh.e[i] = h;
    ll.e[i] = (__bf16)(fv[i] - (float)h);
  }
  *hi = hh.v; *lo = ll.v;
}
__device__ __forceinline__ unsigned short bfbits(float f) {
  const __bf16 h = (__bf16)f;
  unsigned short u; __builtin_memcpy(&u, &h, 2); return u;
}

// ---- prep: G2 = (mask | diag) ? gp : -1.0f (f32), float4-vectorized ----
__global__ __launch_bounds__(256) void k_prep_g2(
    const int* __restrict__ Mask, const float* __restrict__ Gp, float* __restrict__ G2)
{
  const size_t f = (size_t)blockIdx.x * 256 + threadIdx.x;
  const size_t e = f << 2;
  const int k0 = (int)(e & 1023), q = (int)((e >> 10) & 1023);
  const int4 m4 = *(const int4*)(Mask + e);
  const float4 g4 = *(const float4*)(Gp + e);
  float4 r;
  r.x = (m4.x | (q == k0 + 0)) ? g4.x : -1.f;
  r.y = (m4.y | (q == k0 + 1)) ? g4.y : -1.f;
  r.z = (m4.z | (q == k0 + 2)) ? g4.z : -1.f;
  r.w = (m4.w | (q == k0 + 3)) ? g4.w : -1.f;
  *(float4*)(G2 + e) = r;
}

// ---- prep: Wq/Wk/Wv -> bf16, 8 elems/thread ----
__global__ __launch_bounds__(256) void k_prep_w(
    const float* __restrict__ Wq, const float* __restrict__ Wk,
    const float* __restrict__ Wv,
    unsigned short* __restrict__ Qw, unsigned short* __restrict__ Kw,
    unsigned short* __restrict__ Vw)
{
  const int z = blockIdx.z;
  const size_t e = ((size_t)blockIdx.x * 256 + threadIdx.x) * 8;
  const float* S = (z == 0) ? Wq : (z == 1) ? Wk : Wv;
  unsigned short* D = (z == 0) ? Qw : (z == 1) ? Kw : Vw;
  const float4 a = *(const float4*)(S + e);
  const float4 b = *(const float4*)(S + e + 4);
  *(u16x8*)(D + e) = cvt8h(a, b);
}

// ---- QKV GEMM, 128x64 tile, BK=32, bf16 W, single-barrier dbuf, bf16 out ----
__global__ __launch_bounds__(256) void k_gemm_qkv(
    const float* __restrict__ X0, const float* __restrict__ X1, const float* __restrict__ X2,
    const unsigned short* __restrict__ W0, const unsigned short* __restrict__ W1,
    const unsigned short* __restrict__ W2,
    const float* __restrict__ B0, const float* __restrict__ B1, const float* __restrict__ B2,
    unsigned short* __restrict__ O0, unsigned short* __restrict__ O1,
    unsigned short* __restrict__ O2)
{
  const int z = blockIdx.z;
  const float* X = (z == 0) ? X0 : (z == 1) ? X1 : X2;
  const unsigned short* W = (z == 0) ? W0 : (z == 1) ? W1 : W2;
  const float* Bi = (z == 0) ? B0 : (z == 1) ? B1 : B2;
  unsigned short* O = (z == 0) ? O0 : (z == 1) ? O1 : O2;

  const int bid = blockIdx.x;
  const int swz = (bid & 7) * 64 + (bid >> 3);
  const int n0 = (swz & 15) * 64, m0 = (swz >> 4) * 128;

  __shared__ alignas(16) unsigned short Ah[2][128 * GSTR];
  __shared__ alignas(16) unsigned short Bh[2][64 * GSTR];
  const int tid = threadIdx.x, l = tid & 63, w = tid >> 6;
  const int wr = w >> 1, wc = w & 1;

  f32x4 acc[4][2];
#pragma unroll
  for (int i = 0; i < 4; ++i)
#pragma unroll
    for (int j = 0; j < 2; ++j) acc[i][j] = (f32x4){0.f, 0.f, 0.f, 0.f};

  const int arow = tid >> 1, ac0 = (tid & 1) * 16;
  const int brow = tid >> 2, bc0 = (tid & 3) * 8;
  const float* xsrc = X + (size_t)(m0 + arow) * 1024 + ac0;
  const unsigned short* wsrc = W + (size_t)(n0 + brow) * 1024 + bc0;

  float4 fx[4];
  u16x8 bx;
#pragma unroll
  for (int i = 0; i < 4; ++i) fx[i] = *(const float4*)(xsrc + i * 4);
  bx = *(const u16x8*)(wsrc);
  {
    const u16x8 a0 = cvt8h(fx[0], fx[1]), a1 = cvt8h(fx[2], fx[3]);
    lds_write8(&Ah[0][arow * GSTR + ac0], &a0);
    lds_write8(&Ah[0][arow * GSTR + ac0 + 8], &a1);
    lds_write8(&Bh[0][brow * GSTR + bc0], &bx);
  }
#pragma unroll
  for (int i = 0; i < 4; ++i) fx[i] = *(const float4*)(xsrc + 32 + i * 4);
  bx = *(const u16x8*)(wsrc + 32);

  int buf = 0;
  for (int kt = 0; kt < 32; ++kt) {
    __syncthreads();
    if (kt < 31) {
      const u16x8 a0 = cvt8h(fx[0], fx[1]), a1 = cvt8h(fx[2], fx[3]);
      lds_write8(&Ah[buf ^ 1][arow * GSTR + ac0], &a0);
      lds_write8(&Ah[buf ^ 1][arow * GSTR + ac0 + 8], &a1);
      lds_write8(&Bh[buf ^ 1][brow * GSTR + bc0], &bx);
      if (kt < 30) {
        const float* nx = xsrc + (kt + 2) * 32;
#pragma unroll
        for (int i = 0; i < 4; ++i) fx[i] = *(const float4*)(nx + i * 4);
        bx = *(const u16x8*)(wsrc + (kt + 2) * 32);
      }
    }
    bf16x8 ah[4], bh[2];
#pragma unroll
    for (int mf = 0; mf < 4; ++mf) {
      const int r = wr * 64 + mf * 16 + (l & 15);
      ah[mf] = lds_read8(&Ah[buf][r * GSTR + (l >> 4) * 8]);
    }
#pragma unroll
    for (int nf = 0; nf < 2; ++nf) {
      const int r = wc * 32 + nf * 16 + (l & 15);
      bh[nf] = lds_read8(&Bh[buf][r * GSTR + (l >> 4) * 8]);
    }
#pragma unroll
    for (int mf = 0; mf < 4; ++mf)
#pragma unroll
      for (int nf = 0; nf < 2; ++nf)
        acc[mf][nf] = __builtin_amdgcn_mfma_f32_16x16x32_bf16(ah[mf], bh[nf], acc[mf][nf], 0, 0, 0);
    buf ^= 1;
  }

#pragma unroll
  for (int nf = 0; nf < 2; ++nf) {
    const int col = n0 + wc * 32 + nf * 16 + (l & 15);
    const float bias = Bi[col];
#pragma unroll
    for (int mf = 0; mf < 4; ++mf) {
      const int rbase = m0 + wr * 64 + mf * 16 + (l >> 4) * 4;
#pragma unroll
      for (int j = 0; j < 4; ++j)
        O[(size_t)(rbase + j) * 1024 + col] = bfbits(acc[mf][nf][j] + bias);
    }
  }
}

// ---- out-proj GEMM, 64x64 tile, BK=32, bf16 A + in-kernel 2-term W split (R15) ----
__global__ __launch_bounds__(256) void k_gemm_out(
    const unsigned short* __restrict__ X, const float* __restrict__ W,
    const float* __restrict__ Bi, float* __restrict__ Out)
{
  const int bid = blockIdx.x;
  const int swz = (bid & 7) * 128 + (bid >> 3);
  const int n0 = (swz & 15) * 64, m0 = (swz >> 4) * 64;

  __shared__ alignas(16) unsigned short Ah[64 * GSTR];
  __shared__ alignas(16) unsigned short Bh[64 * GSTR], Bl[64 * GSTR];
  const int tid = threadIdx.x, l = tid & 63, w = tid >> 6;
  const int wr = w >> 1, wc = w & 1;

  f32x4 acc[2][2];
#pragma unroll
  for (int i = 0; i < 2; ++i)
#pragma unroll
    for (int j = 0; j < 2; ++j) acc[i][j] = (f32x4){0.f, 0.f, 0.f, 0.f};

  const int srow = tid >> 2, sc0 = (tid & 3) * 8;
  const unsigned short* xsrc = X + (size_t)(m0 + srow) * 1024 + sc0;
  const float* wsrc = W + (size_t)(n0 + srow) * 1024 + sc0;

  u16x8 xcur = *(const u16x8*)xsrc;
  float4 fw[2];
#pragma unroll
  for (int i = 0; i < 2; ++i) fw[i] = *(const float4*)(wsrc + i * 4);

  for (int kt = 0; kt < 32; ++kt) {
    const u16x8 xstage = xcur;
    u16x8 wh1, wl1;
    cvt8hl(fw[0], fw[1], &wh1, &wl1);
    if (kt < 31) {
      xcur = *(const u16x8*)(xsrc + (kt + 1) * 32);
      const float* nw = wsrc + (kt + 1) * 32;
#pragma unroll
      for (int i = 0; i < 2; ++i) fw[i] = *(const float4*)(nw + i * 4);
    }
    __syncthreads();
    lds_write8(&Ah[srow * GSTR + sc0], &xstage);
    lds_write8(&Bh[srow * GSTR + sc0], &wh1);
    lds_write8(&Bl[srow * GSTR + sc0], &wl1);
    __syncthreads();

    bf16x8 ah[2], bh[2], bl[2];
#pragma unroll
    for (int mf = 0; mf < 2; ++mf) {
      const int r = wr * 32 + mf * 16 + (l & 15);
      ah[mf] = lds_read8(&Ah[r * GSTR + (l >> 4) * 8]);
    }
#pragma unroll
    for (int nf = 0; nf < 2; ++nf) {
      const int r = wc * 32 + nf * 16 + (l & 15);
      bh[nf] = lds_read8(&Bh[r * GSTR + (l >> 4) * 8]);
      bl[nf] = lds_read8(&Bl[r * GSTR + (l >> 4) * 8]);
    }
#pragma unroll
    for (int mf = 0; mf < 2; ++mf)
#pragma unroll
      for (int nf = 0; nf < 2; ++nf) {
        acc[mf][nf] = __builtin_amdgcn_mfma_f32_16x16x32_bf16(ah[mf], bh[nf], acc[mf][nf], 0, 0, 0);
        acc[mf][nf] = __builtin_amdgcn_mfma_f32_16x16x32_bf16(ah[mf], bl[nf], acc[mf][nf], 0, 0, 0);
      }
  }

#pragma unroll
  for (int nf = 0; nf < 2; ++nf) {
    const int col = n0 + wc * 32 + nf * 16 + (l & 15);
    const float bias = Bi[col];
#pragma unroll
    for (int mf = 0; mf < 2; ++mf) {
      const int rbase = m0 + wr * 32 + mf * 16 + (l >> 4) * 4;
#pragma unroll
      for (int j = 0; j < 4; ++j)
        Out[(size_t)(rbase + j) * 1024 + col] = acc[mf][nf][j] + bias;
    }
  }
}

// ---------------- fused attention (R15 exact: G2 f32) ----------------
__global__ __launch_bounds__(256) void k_attn(
    const unsigned short* Qh, const unsigned short* __restrict__ Kb,
    const unsigned short* __restrict__ Vb,
    const float* __restrict__ G2, unsigned short* Xo)
{
  const int i = blockIdx.x;
  const int xc = i & 7, kk_ = i >> 3;
  const int h = kk_ & 15, g = kk_ >> 4;
  const int qb = g * 8 + xc;
  const int qt = qb >> 2, b = qb & 3;

  __shared__ alignas(16) unsigned short Kh[2][64 * 64];
  __shared__ alignas(16) unsigned short Vh[64 * 64];
  __shared__ alignas(16) unsigned short Ph[64 * 64];
  const int tid = threadIdx.x, l = tid & 63, w = tid >> 6;

  const unsigned short* kb_ = Kb + (size_t)b * 1048576 + h * 64;
  const unsigned short* vb_ = Vb + (size_t)b * 1048576 + h * 64;

  bf16x8 aq[2];
  {
    const int qrow = qt * 64 + w * 16 + (l & 15);
    const unsigned short* qp_ = Qh + ((size_t)(b * 1024 + qrow)) * 1024 + h * 64;
    aq[0] = lds_read8(qp_ + (l >> 4) * 8);
    aq[1] = lds_read8(qp_ + 32 + (l >> 4) * 8);
  }

  f32x4 accO[4];
#pragma unroll
  for (int nf = 0; nf < 4; ++nf) accO[nf] = (f32x4){0.f, 0.f, 0.f, 0.f};
  float zacc[4] = {0.f, 0.f, 0.f, 0.f};

  const int qloc0 = w * 16 + (l >> 4) * 4;
  const int qg0 = qt * 64 + qloc0;
  const int mcol = l & 15;

  const float* grow[4];
#pragma unroll
  for (int j = 0; j < 4; ++j)
    grow[j] = G2 + (((size_t)(b * 1024 + qg0 + j)) << 10) + mcol;

  const int srcg8 = ((l & 7) ^ (l >> 3)) * 8;
  const int rowl = l >> 3;
  const int kb4 = (tid & 15) * 4, db4 = (tid >> 4) * 4;
  union U4 { unsigned int u[2]; unsigned short s[4]; };
  U4 vr[4];

#pragma unroll
  for (int I = 0; I < 2; ++I)
    gload_lds16(kb_ + (size_t)(I * 32 + w * 8 + rowl) * 1024 + srcg8,
                &Kh[0][I * 2048 + w * 512]);
#pragma unroll
  for (int ii = 0; ii < 4; ++ii)
    __builtin_memcpy(&vr[ii], vb_ + (size_t)(kb4 + ii) * 1024 + db4, 8);

  float gcur[4][4], gnext[4][4];
#pragma unroll
  for (int nf = 0; nf < 4; ++nf)
#pragma unroll
    for (int j = 0; j < 4; ++j) gcur[nf][j] = grow[j][nf * 16];

  int buf = 0;
  for (int kt = 0; kt < 16; ++kt) {
    __syncthreads();  // B1: drains K[buf] gl_lds + vr loads; prev tile consumed

#pragma unroll
    for (int ii = 0; ii < 4; ++ii) {
      const int d = db4 + ii;
      union { unsigned short s[4]; unsigned long long v; } pk;
#pragma unroll
      for (int u = 0; u < 4; ++u) pk.s[u] = vr[u].s[ii];
      const int c = kb4 ^ ((d & 7) << 3);
      __builtin_memcpy(__builtin_assume_aligned(&Vh[d * 64 + c], 8), &pk.v, 8);
    }
    __syncthreads();  // B2: V + K[buf] ready

    if (kt < 15) {
#pragma unroll
      for (int I = 0; I < 2; ++I)
        gload_lds16(kb_ + (size_t)((kt + 1) * 64 + I * 32 + w * 8 + rowl) * 1024 + srcg8,
                    &Kh[buf ^ 1][I * 2048 + w * 512]);
#pragma unroll
      for (int ii = 0; ii < 4; ++ii)
        __builtin_memcpy(&vr[ii], vb_ + (size_t)((kt + 1) * 64 + kb4 + ii) * 1024 + db4, 8);
#pragma unroll
      for (int nf = 0; nf < 4; ++nf)
#pragma unroll
        for (int j = 0; j < 4; ++j) gnext[nf][j] = grow[j][(kt + 1) * 64 + nf * 16];
    }

#pragma unroll
    for (int nf = 0; nf < 4; ++nf) {
      f32x4 sacc = (f32x4){0.f, 0.f, 0.f, 0.f};
      const int kr = nf * 16 + (l & 15);
#pragma unroll
      for (int ks = 0; ks < 2; ++ks) {
        const int c = (ks * 32 + (l >> 4) * 8) ^ ((kr & 7) << 3);
        sacc = __builtin_amdgcn_mfma_f32_16x16x32_bf16(aq[ks], lds_read8(&Kh[buf][kr * 64 + c]), sacc, 0, 0, 0);
      }
#pragma unroll
      for (int j = 0; j < 4; ++j) {
        const float g2 = gcur[nf][j];
        const float e = (g2 >= 0.f) ? exp2f(fmaf(sacc[j], 0.18033688f, -17.31234049f)) : 0.f;
        zacc[j] += e;
        const int qloc = qloc0 + j;
        Ph[qloc * 64 + ((nf * 16 + mcol) ^ ((qloc & 7) << 3))] = bfbits(e * g2);
      }
    }
    bf16x8 pah[2];
    {
      const int ar = w * 16 + (l & 15);
#pragma unroll
      for (int ks = 0; ks < 2; ++ks) {
        const int c = (ks * 32 + (l >> 4) * 8) ^ ((ar & 7) << 3);
        pah[ks] = lds_read8(&Ph[ar * 64 + c]);
      }
    }
#pragma unroll
    for (int nf = 0; nf < 4; ++nf) {
      const int dr = nf * 16 + (l & 15);
#pragma unroll
      for (int ks = 0; ks < 2; ++ks) {
        const int c = (ks * 32 + (l >> 4) * 8) ^ ((dr & 7) << 3);
        accO[nf] = __builtin_amdgcn_mfma_f32_16x16x32_bf16(pah[ks], lds_read8(&Vh[dr * 64 + c]), accO[nf], 0, 0, 0);
      }
    }
    buf ^= 1;
#pragma unroll
    for (int nf = 0; nf < 4; ++nf)
#pragma unroll
      for (int j = 0; j < 4; ++j) gcur[nf][j] = gnext[nf][j];
  }

#pragma unroll
  for (int j = 0; j < 4; ++j) {
#pragma unroll
    for (int off = 1; off < 16; off <<= 1) zacc[j] += __shfl_xor(zacc[j], off, 64);
  }
  float rz[4];
#pragma unroll
  for (int j = 0; j < 4; ++j) rz[j] = 1.f / zacc[j];

#pragma unroll
  for (int nf = 0; nf < 4; ++nf) {
    const int d = nf * 16 + (l & 15);
#pragma unroll
    for (int j = 0; j < 4; ++j) {
      const int qg = qg0 + j;
      Xo[((size_t)(b * 1024 + qg)) * 1024 + h * 64 + d] = bfbits(accO[nf][j] * rz[j]);
    }
  }
}

extern "C" void kernel_launch(void* const* d_in, const int* in_sizes, int n_in,
                              void* d_out, int out_size, void* d_ws, size_t ws_size,
                              hipStream_t stream) {
  const float* query = (const float*)d_in[0];
  const float* key_in = (const float*)d_in[1];
  const float* value = (const float*)d_in[2];
  const int* mask = (const int*)d_in[3];
  const float* gp = (const float*)d_in[4];
  const float* Wq = (const float*)d_in[5];
  const float* bq = (const float*)d_in[6];
  const float* Wk = (const float*)d_in[7];
  const float* bk = (const float*)d_in[8];
  const float* Wv = (const float*)d_in[9];
  const float* bv = (const float*)d_in[10];
  const float* Wo = (const float*)d_in[11];
  const float* bo = (const float*)d_in[12];
  float* out = (float*)d_out;

  // Workspace 46MB (<48 proven): kp,vp,qp bf16 (xo aliases qp), g2 f32, wqkv bf16.
  unsigned short* kp = (unsigned short*)d_ws;
  unsigned short* vp = kp + 4194304;
  unsigned short* qp = vp + 4194304;
  unsigned short* xo = qp;
  float* g2 = (float*)(qp + 4194304);
  unsigned short* wq = (unsigned short*)(g2 + 4194304);
  unsigned short* wk = wq + 1048576;
  unsigned short* wv = wk + 1048576;

  hipLaunchKernelGGL(k_prep_g2, dim3(4096), dim3(256), 0, stream, mask, gp, g2);
  hipLaunchKernelGGL(k_prep_w, dim3(512, 1, 3), dim3(256), 0, stream,
                     Wq, Wk, Wv, wq, wk, wv);
  hipLaunchKernelGGL(k_gemm_qkv, dim3(512, 1, 3), dim3(256), 0, stream,
                     query, key_in, value, wq, wk, wv, bq, bk, bv, qp, kp, vp);
  hipLaunchKernelGGL(k_attn, dim3(1024), dim3(256), 0, stream,
                     qp, kp, vp, g2, xo);
  hipLaunchKernelGGL(k_gemm_out, dim3(1024), dim3(256), 0, stream,
                     xo, Wo, bo, out);
}